// Round 4
// baseline (537.270 us; speedup 1.0000x reference)
//
#include <hip/hip_runtime.h>

typedef unsigned short u16;
typedef __attribute__((ext_vector_type(8))) short s16x8;   // 8 bf16 in 4 VGPRs
typedef __attribute__((ext_vector_type(4))) float f32x4;

#define MFMA_BF16(a,b,c) __builtin_amdgcn_mfma_f32_16x16x32_bf16((a),(b),(c),0,0,0)

// async global->LDS, 16B per lane. LDS dest is wave-uniform base + lane*16;
// our staging layouts are lane-linear so per-lane pointer == base + lane*16.
#define GLL(gp, lp) __builtin_amdgcn_global_load_lds( \
    (const __attribute__((address_space(1))) void*)(gp), \
    (__attribute__((address_space(3))) void*)(lp), 16, 0, 0)

// counted-vmcnt barrier: wait for all but the newest N vmem ops, then s_barrier.
// asm memory clobber + sched_barrier(0) fence per guide rule #18.
#define PIPE_WAIT_BAR(N) do { \
  asm volatile("s_waitcnt vmcnt(" #N ")" ::: "memory"); \
  __builtin_amdgcn_sched_barrier(0); \
  __builtin_amdgcn_s_barrier(); \
  __builtin_amdgcn_sched_barrier(0); \
} while (0)

#define PIPE_BAR() do { \
  asm volatile("" ::: "memory"); \
  __builtin_amdgcn_sched_barrier(0); \
  __builtin_amdgcn_s_barrier(); \
  __builtin_amdgcn_sched_barrier(0); \
} while (0)

__device__ __forceinline__ float b2f(u16 s){
  union { unsigned u; float f; } v; v.u = ((unsigned)s) << 16; return v.f;
}
__device__ __forceinline__ u16 f2b(float x){
  union { float f; unsigned u; } v; v.f = x;
  unsigned u = v.u;
  return (u16)((u + 0x7FFFu + ((u >> 16) & 1u)) >> 16);   // round-to-nearest-even
}
__device__ __forceinline__ u16 f2b_trunc(float x){
  union { float f; unsigned u; } v; v.f = x;
  return (u16)(v.u >> 16);                                 // truncate (softmax-safe)
}

// exact-enough GELU: erf via Abramowitz-Stegun 7.1.26 (max abs err 1.5e-7,
// far below bf16 ulp) — ~12 VALU ops vs libm erff's ~60+.
__device__ __forceinline__ float gelu_fast(float v){
  float av = fabsf(v) * 0.70710678118654752f;
  float t  = __builtin_amdgcn_rcpf(1.0f + 0.3275911f * av);
  float p  = ((((1.061405429f * t - 1.453152027f) * t + 1.421413741f) * t
               - 0.284496736f) * t + 0.254829592f) * t;
  float erfa = 1.0f - p * __expf(-av * av);
  return 0.5f * v * (1.0f + copysignf(erfa, v));
}

// ---------------- all weight converts in one dispatch (f32 [K][N] -> bf16 [N][K]) ----------------
__global__ __launch_bounds__(256) void wconv_all(
    const float* __restrict__ w0, u16* __restrict__ t0,   // qkv  256x768
    const float* __restrict__ w1, u16* __restrict__ t1,   // proj 256x256
    const float* __restrict__ w2, u16* __restrict__ t2,   // fc   256x1024
    const float* __restrict__ w3, u16* __restrict__ t3)   // fc2  1024x256
{
  int bid = blockIdx.x;
  const float* w; u16* t; int K, N, base;
  if (bid < 768)        { w = w0; t = t0; K = 256;  N = 768;  base = bid; }
  else if (bid < 1024)  { w = w1; t = t1; K = 256;  N = 256;  base = bid - 768; }
  else if (bid < 2048)  { w = w2; t = t2; K = 256;  N = 1024; base = bid - 1024; }
  else                  { w = w3; t = t3; K = 1024; N = 256;  base = bid - 2048; }
  int idx = base * 256 + threadIdx.x;
  if (idx >= K * N) return;
  int k = idx / N, n = idx - k * N;
  t[(size_t)n * K + k] = f2b(w[idx]);
}

// ---------------- LayerNorm over C=256, one wave per row; f32 in -> bf16 out ----------------
__global__ __launch_bounds__(256) void ln_f32(const float* __restrict__ in,
    const float* __restrict__ gam, const float* __restrict__ bet, u16* __restrict__ out)
{
  int wv = threadIdx.x >> 6, lane = threadIdx.x & 63;
  size_t row = (size_t)blockIdx.x * 4 + wv;
  float4 u = *(const float4*)(in + row * 256 + lane * 4);
  float s  = u.x + u.y + u.z + u.w;
  float s2 = u.x*u.x + u.y*u.y + u.z*u.z + u.w*u.w;
  #pragma unroll
  for (int off = 32; off; off >>= 1){
    s  += __shfl_xor(s, off);
    s2 += __shfl_xor(s2, off);
  }
  float mean = s * (1.0f/256.0f);
  float var  = s2 * (1.0f/256.0f) - mean*mean;
  float rs   = rsqrtf(var + 1e-5f);
  int c = lane * 4;
  float4 g4 = *(const float4*)(gam + c);
  float4 b4 = *(const float4*)(bet + c);
  ushort4 o;
  o.x = f2b((u.x - mean)*rs*g4.x + b4.x);
  o.y = f2b((u.y - mean)*rs*g4.y + b4.y);
  o.z = f2b((u.z - mean)*rs*g4.z + b4.z);
  o.w = f2b((u.w - mean)*rs*g4.w + b4.w);
  *(ushort4*)(out + row * 256 + c) = o;
}

// ---------------- 128x128-tile bf16 MFMA GEMM, XCD-swizzled 1D grid ----------------
// DEPTH-3 global_load_lds pipeline (triple-buffered LDS, vmcnt(8) in-loop).
// Epilogue: LDS-staged chunks; readback stores full contiguous 128B lines.
// EPI 0: QKV scatter (+bias) -> o0=q (PRE-SCALED by 1/sqrt(32)), o1=k, o2=v, [bah][t][d] bf16
template<int EPI, int NT>
__global__ __launch_bounds__(256) void gemm128(
    const u16* __restrict__ A, const u16* __restrict__ Bt, const float* __restrict__ bias,
    const u16* __restrict__ res, void* __restrict__ o0v, u16* __restrict__ o1, u16* __restrict__ o2,
    int N, int K)
{
  __shared__ __align__(16) u16 lds[24576];
  int tid = threadIdx.x;
  int w = tid >> 6, lane = tid & 63;
  int quad = lane >> 4, c = lane & 15;
  int bid = blockIdx.x;
  int x = bid & 7, j = bid >> 3;
  int nt = j % NT, mt = (j / NT) * 8 + x;
  int wm = (w >> 1) * 64, wn = (w & 1) * 64;
  const u16* Abase = A + (size_t)mt * 128 * K;
  const u16* Bbase = Bt + (size_t)nt * 128 * K;
  int m0 = tid & 127, jj0 = tid >> 7;
  f32x4 zero = {0.f, 0.f, 0.f, 0.f};
  f32x4 acc[4][4];
  #pragma unroll
  for (int mi = 0; mi < 4; mi++)
    #pragma unroll
    for (int ni = 0; ni < 4; ni++) acc[mi][ni] = zero;

  auto stage = [&](int buf, int k0){
    u16* base = &lds[buf * 8192];
    GLL(Abase + (size_t)m0 * K + k0 + jj0 * 8,       &base[tid * 8]);
    GLL(Abase + (size_t)m0 * K + k0 + (jj0 + 2) * 8, &base[2048 + tid * 8]);
    GLL(Bbase + (size_t)m0 * K + k0 + jj0 * 8,       &base[4096 + tid * 8]);
    GLL(Bbase + (size_t)m0 * K + k0 + (jj0 + 2) * 8, &base[6144 + tid * 8]);
  };
  auto compute = [&](int cb){
    const u16* Lb = &lds[cb * 8192];
    s16x8 af[4], bfr[4];
    #pragma unroll
    for (int mi = 0; mi < 4; mi++)
      af[mi] = *(const s16x8*)&Lb[(quad * 128 + wm + mi * 16 + c) * 8];
    #pragma unroll
    for (int ni = 0; ni < 4; ni++)
      bfr[ni] = *(const s16x8*)&Lb[4096 + (quad * 128 + wn + ni * 16 + c) * 8];
    #pragma unroll
    for (int mi = 0; mi < 4; mi++)
      #pragma unroll
      for (int ni = 0; ni < 4; ni++)
        acc[mi][ni] = MFMA_BF16(af[mi], bfr[ni], acc[mi][ni]);
  };

  stage(0, 0); stage(1, 32); stage(2, 64);
  int cur = 0;
  int k0 = 0;
  for (; k0 + 96 < K; k0 += 32){
    PIPE_WAIT_BAR(8);
    compute(cur);
    PIPE_BAR();
    stage(cur, k0 + 96);
    cur = (cur == 2) ? 0 : cur + 1;
  }
  PIPE_WAIT_BAR(8); compute(cur); cur = (cur == 2) ? 0 : cur + 1;
  PIPE_WAIT_BAR(4); compute(cur); cur = (cur == 2) ? 0 : cur + 1;
  PIPE_WAIT_BAR(0); compute(cur);

  // LDS-staged coalesced epilogue (full 128B-line stores)
  const int LS  = 132;
  int rr = tid >> 3;
  int c7 = tid & 7;

  #pragma unroll
  for (int ch = 0; ch < 4; ch++){
    __syncthreads();
    if ((w >> 1) == (ch >> 1)){
      #pragma unroll
      for (int mi2 = 0; mi2 < 2; mi2++){
        int mi = (ch & 1) * 2 + mi2;
        #pragma unroll
        for (int ni = 0; ni < 4; ni++){
          int col = wn + ni * 16 + c;
          float bv = bias[nt * 128 + col];
          #pragma unroll
          for (int r = 0; r < 4; r++){
            int cr = mi2 * 16 + quad * 4 + r;
            float vv = acc[mi][ni][r] + bv;
            if (EPI == 0){
              int gcol = nt * 128 + col;
              if ((gcol >> 8) == 0) vv *= 0.17677669529663687f;   // q pre-scale
              lds[cr * LS + col] = f2b(vv);
            }
          }
        }
      }
    }
    __syncthreads();
    int row = mt * 128 + ch * 32 + rr;
    #pragma unroll
    for (int jj2 = 0; jj2 < 2; jj2++){
      int colL = c7 * 8 + jj2 * 64;
      uint4 val = *(const uint4*)&lds[rr * LS + colL];
      if (EPI == 0){
        int gcol = nt * 128 + colL;
        int which = gcol >> 8, ccc = gcol & 255;
        int hh = ccc >> 5, d = ccc & 31;
        int ba = row >> 9, t = row & 511;
        size_t idx = (((size_t)(ba * 8 + hh)) * 512 + t) * 32 + d;
        u16* dst = (which == 0) ? (u16*)o0v : ((which == 1) ? o1 : o2);
        *(uint4*)(dst + idx) = val;
      } else {
        *(uint4*)((u16*)o0v + (size_t)row * N + nt * 128 + colL) = val;
      }
    }
  }
}

// ---------------- fused FFN: out = x2n + (gelu(x2n@fc_w + fc_b) @ fc2_w + fc2_b) ----------------
// One block = 64 rows, 256 threads (4 waves; wave w owns out cols [64w,64w+64)).
// x2n tile (64x256 bf16, 32KB) staged ONCE via GLL with pre-swizzled global src
// (XOR involution (row&7)<<4 on the 512B row) so ds_read_b128 A-frags are
// conflict-free. h never hits global: per 128-col hid-chunk, GEMM1 -> gelu ->
// swizzled h LDS (16KB, XOR (row&15)<<4) -> GEMM2 accumulates into persistent
// acc2. Weights (0.5MB each) are NOT LDS-staged: fragments gathered directly
// from L2 (guide: don't stage what L2-fits). Epilogue folds fc2_b + residual
// (x2n read from LDS), bounces f32 through LDS, stores full 128B lines.
// Deletes 134MB h write + 134MB h read + 33MB residual re-read vs split FC1/FC2.
__global__ __launch_bounds__(256) void ffn_fused(
    const u16* __restrict__ x2n, const u16* __restrict__ fcT, const float* __restrict__ fcb,
    const u16* __restrict__ fc2T, const float* __restrict__ fc2b, float* __restrict__ out)
{
  // u16 units: x2n tile [0, 16384) = 32KB; h chunk [16384, 24576) = 16KB.
  // f32 epilogue bounce (32 rows x 260 f32 = 33280B) reuses [0, 16640).
  __shared__ __align__(16) u16 lds[24576];
  int tid = threadIdx.x;
  int w = tid >> 6, lane = tid & 63;
  int quad = lane >> 4, c = lane & 15;
  int mt = blockIdx.x;                                 // 64-row tile
  const u16* Abase = x2n + (size_t)mt * 64 * 256;
  char* ldsc = (char*)lds;
  char* hl   = (char*)lds + 32768;

  // ---- stage x2n swizzled: LDS byte o=ci*16 holds global (row*512 + (o&511)^((row&7)<<4))
  #pragma unroll
  for (int i = 0; i < 8; i++){
    int ci = i * 256 + tid;
    int row = ci >> 5, slot = ci & 31;
    int glow = (slot * 16) ^ ((row & 7) << 4);
    GLL((const char*)Abase + row * 512 + glow, ldsc + ci * 16);
  }
  f32x4 zero = {0.f, 0.f, 0.f, 0.f};
  f32x4 acc2[4][4];
  #pragma unroll
  for (int mi = 0; mi < 4; mi++)
    #pragma unroll
    for (int ni = 0; ni < 4; ni++) acc2[mi][ni] = zero;
  PIPE_WAIT_BAR(0);

  for (int hc = 0; hc < 8; hc++){
    // ---- GEMM1: h_chunk[64][128] = x2n_tile @ fc_w[:, hc*128:+128)
    f32x4 acc1[4][2];
    #pragma unroll
    for (int mi = 0; mi < 4; mi++){ acc1[mi][0] = zero; acc1[mi][1] = zero; }
    #pragma unroll
    for (int ks = 0; ks < 8; ks++){
      s16x8 af[4], bf1[2];
      #pragma unroll
      for (int ni = 0; ni < 2; ni++){
        int n = hc * 128 + w * 32 + ni * 16 + c;
        bf1[ni] = *(const s16x8*)(fcT + (size_t)n * 256 + ks * 32 + quad * 8);
      }
      #pragma unroll
      for (int mi = 0; mi < 4; mi++){
        int row = mi * 16 + c;
        int kb = (ks * 64 + quad * 16) ^ ((row & 7) << 4);
        af[mi] = *(const s16x8*)(ldsc + row * 512 + kb);
      }
      #pragma unroll
      for (int mi = 0; mi < 4; mi++){
        acc1[mi][0] = MFMA_BF16(af[mi], bf1[0], acc1[mi][0]);
        acc1[mi][1] = MFMA_BF16(af[mi], bf1[1], acc1[mi][1]);
      }
    }
    __syncthreads();   // previous chunk's GEMM2 h-reads complete
    // ---- gelu -> bf16 h chunk (swizzled)
    #pragma unroll
    for (int ni = 0; ni < 2; ni++){
      int colc = w * 32 + ni * 16 + c;                 // chunk-local h col [0,128)
      float bv = fcb[hc * 128 + colc];
      #pragma unroll
      for (int mi = 0; mi < 4; mi++){
        #pragma unroll
        for (int r = 0; r < 4; r++){
          int row = mi * 16 + quad * 4 + r;
          int by = (colc * 2) ^ ((row & 15) << 4);
          *(u16*)(hl + row * 256 + by) = f2b(gelu_fast(acc1[mi][ni][r] + bv));
        }
      }
    }
    __syncthreads();   // h visible to all
    // ---- GEMM2 partial: acc2 += h_chunk @ fc2_w[hc*128:+128, :]
    #pragma unroll
    for (int ks = 0; ks < 4; ks++){
      s16x8 ha[4], bf2[4];
      #pragma unroll
      for (int ni = 0; ni < 4; ni++){
        int n = w * 64 + ni * 16 + c;
        bf2[ni] = *(const s16x8*)(fc2T + (size_t)n * 1024 + hc * 128 + ks * 32 + quad * 8);
      }
      #pragma unroll
      for (int mi = 0; mi < 4; mi++){
        int row = mi * 16 + c;
        int kb = (ks * 64 + quad * 16) ^ ((row & 15) << 4);
        ha[mi] = *(const s16x8*)(hl + row * 256 + kb);
      }
      #pragma unroll
      for (int mi = 0; mi < 4; mi++)
        #pragma unroll
        for (int ni = 0; ni < 4; ni++)
          acc2[mi][ni] = MFMA_BF16(ha[mi], bf2[ni], acc2[mi][ni]);
    }
  }

  // ---- fold bias + residual (x2n from LDS) into acc2
  #pragma unroll
  for (int ni = 0; ni < 4; ni++){
    int col = w * 64 + ni * 16 + c;
    float bv = fc2b[col];
    #pragma unroll
    for (int mi = 0; mi < 4; mi++){
      #pragma unroll
      for (int r = 0; r < 4; r++){
        int row = mi * 16 + quad * 4 + r;
        int by = (col * 2) ^ ((row & 7) << 4);
        u16 xv = *(const u16*)(ldsc + row * 512 + by);
        acc2[mi][ni][r] += bv + b2f(xv);
      }
    }
  }
  __syncthreads();   // all LDS reads (residual + h) done before bounce overwrite

  // ---- f32 bounce: 2 chunks of 32 rows, fully-coalesced 128B-line stores
  float* ldsF = (float*)lds;
  const int LSO = 260;
  int rr = tid >> 3, c8 = tid & 7;
  #pragma unroll
  for (int ch = 0; ch < 2; ch++){
    #pragma unroll
    for (int mi2 = 0; mi2 < 2; mi2++){
      int mi = ch * 2 + mi2;
      #pragma unroll
      for (int ni = 0; ni < 4; ni++){
        #pragma unroll
        for (int r = 0; r < 4; r++){
          int crow = mi2 * 16 + quad * 4 + r;
          ldsF[crow * LSO + w * 64 + ni * 16 + c] = acc2[mi][ni][r];
        }
      }
    }
    __syncthreads();
    size_t rb = ((size_t)mt * 64 + ch * 32 + rr) * 256;
    #pragma unroll
    for (int jj = 0; jj < 8; jj++){
      int col = c8 * 4 + jj * 32;
      *(float4*)(out + rb + col) = *(const float4*)&ldsF[rr * LSO + col];
    }
    __syncthreads();
  }
}

// ---------------- fused proj GEMM + residual + LayerNorm2 -> x2n ----------------
// 2-phase global_load_lds pipeline (5 loads/stage -> vmcnt(5)).
__global__ __launch_bounds__(256) void proj_ln(
    const u16* __restrict__ A, const u16* __restrict__ Bt, const float* __restrict__ bias,
    const u16* __restrict__ res, const float* __restrict__ gam, const float* __restrict__ bet,
    u16* __restrict__ x2n)
{
  __shared__ __align__(16) u16 lds[20480];
  int tid = threadIdx.x;
  int w = tid >> 6, lane = tid & 63;
  int quad = lane >> 4, c = lane & 15;
  int mt = blockIdx.x;
  int wn = w * 64;
  const u16* Abase = A + (size_t)mt * 64 * 256;
  int an = tid & 63, aj = tid >> 6;
  f32x4 zero = {0.f, 0.f, 0.f, 0.f};
  f32x4 acc[4][4];
  #pragma unroll
  for (int mi = 0; mi < 4; mi++)
    #pragma unroll
    for (int ni = 0; ni < 4; ni++) acc[mi][ni] = zero;

  auto stage = [&](int buf, int k0){
    u16* base = &lds[buf * 10240];
    GLL(Abase + (size_t)an * 256 + k0 + aj * 8, &base[tid * 8]);
    #pragma unroll
    for (int i = 0; i < 4; i++){
      int ci = tid + i * 256;
      int n = ci & 255, jjb = ci >> 8;
      GLL(Bt + (size_t)n * 256 + k0 + jjb * 8, &base[2048 + ci * 8]);
    }
  };
  auto compute = [&](int cb){
    const u16* base = &lds[cb * 10240];
    s16x8 af[4], bfr[4];
    #pragma unroll
    for (int mi = 0; mi < 4; mi++)
      af[mi] = *(const s16x8*)&base[(quad * 64 + mi * 16 + c) * 8];
    #pragma unroll
    for (int ni = 0; ni < 4; ni++)
      bfr[ni] = *(const s16x8*)&base[2048 + (quad * 256 + wn + ni * 16 + c) * 8];
    #pragma unroll
    for (int mi = 0; mi < 4; mi++)
      #pragma unroll
      for (int ni = 0; ni < 4; ni++)
        acc[mi][ni] = MFMA_BF16(af[mi], bfr[ni], acc[mi][ni]);
  };

  stage(0, 0);
  int cur = 0;
  for (int k0 = 32; k0 < 256; k0 += 32){
    stage(cur ^ 1, k0);
    PIPE_WAIT_BAR(5);
    compute(cur);
    PIPE_BAR();
    cur ^= 1;
  }
  PIPE_WAIT_BAR(0);
  compute(cur);
  __syncthreads();

  #pragma unroll
  for (int ni = 0; ni < 4; ni++){
    int col = wn + ni * 16 + c;
    float bv = bias[col];
    #pragma unroll
    for (int mi = 0; mi < 4; mi++){
      #pragma unroll
      for (int r = 0; r < 4; r++){
        int rowL = mi * 16 + quad * 4 + r;
        size_t gidx = ((size_t)mt * 64 + rowL) * 256 + col;
        lds[rowL * 264 + col] = f2b(acc[mi][ni][r] + bv + b2f(res[gidx]));
      }
    }
  }
  __syncthreads();

  int rowL = tid >> 2, part = (tid & 3) * 64;
  float s = 0.f, s2 = 0.f;
  #pragma unroll
  for (int i = 0; i < 16; i++){
    ushort4 u = *(const ushort4*)&lds[rowL * 264 + part + i * 4];
    float v0 = b2f(u.x), v1 = b2f(u.y), v2 = b2f(u.z), v3 = b2f(u.w);
    s  += v0 + v1 + v2 + v3;
    s2 += v0*v0 + v1*v1 + v2*v2 + v3*v3;
  }
  s  += __shfl_xor(s, 1);  s  += __shfl_xor(s, 2);
  s2 += __shfl_xor(s2, 1); s2 += __shfl_xor(s2, 2);
  float mean = s * (1.0f/256.0f);
  float var  = s2 * (1.0f/256.0f) - mean*mean;
  float rs   = rsqrtf(var + 1e-5f);
  size_t orow = ((size_t)mt * 64 + rowL) * 256;
  #pragma unroll
  for (int i = 0; i < 16; i++){
    int col = part + i * 4;
    ushort4 u = *(const ushort4*)&lds[rowL * 264 + col];
    float4 g4 = *(const float4*)(gam + col);
    float4 b4 = *(const float4*)(bet + col);
    ushort4 o;
    o.x = f2b((b2f(u.x) - mean)*rs*g4.x + b4.x);
    o.y = f2b((b2f(u.y) - mean)*rs*g4.y + b4.y);
    o.z = f2b((b2f(u.z) - mean)*rs*g4.z + b4.z);
    o.w = f2b((b2f(u.w) - mean)*rs*g4.w + b4.w);
    *(ushort4*)(x2n + orow + col) = o;
  }
}

// ---------------- flash attention, no-max softmax; XCD-swizzled 1D grid ----------------
__global__ __launch_bounds__(256) void attn_kernel(const u16* __restrict__ q,
    const u16* __restrict__ k, const u16* __restrict__ v, u16* __restrict__ y)
{
  __shared__ __align__(16) u16 ldsK[32 * 36];    // [s][d], row stride 36
  __shared__ __align__(16) u16 ldsV[32 * 36];    // [d][s], row stride 36
  __shared__ __align__(16) u16 ldsp[4][16 * 36]; // per-wave P [prow][s], stride 36
  int tid = threadIdx.x;
  int w = tid >> 6, lane = tid & 63;
  int quad = lane >> 4, c = lane & 15;
  int bid = blockIdx.x;
  int x = bid & 7, j = bid >> 3;
  int qt = j & 3, bah = (j >> 2) * 8 + x;
  int q0 = qt * 128 + w * 32;
  const u16* qb = q + (size_t)bah * 16384;
  const u16* kb = k + (size_t)bah * 16384;
  const u16* vb = v + (size_t)bah * 16384;
  int krow = tid >> 3, kcol = (tid & 7) * 4;     // K staging: uint2 per thread
  int vd = tid & 31,  vs = (tid >> 5) * 4;       // V staging: 4 strided u16 -> b64

  s16x8 qf0 = *(const s16x8*)(qb + (q0 + c) * 32 + quad * 8);
  s16x8 qf1 = *(const s16x8*)(qb + (q0 + 16 + c) * 32 + quad * 8);
  float l0[4] = {0.f,0.f,0.f,0.f}, l1[4] = {0.f,0.f,0.f,0.f};
  f32x4 o00 = {0,0,0,0}, o01 = {0,0,0,0}, o10 = {0,0,0,0}, o11 = {0,0,0,0};
  f32x4 zero = {0,0,0,0};

  for (int s0 = 0; s0 < 512; s0 += 32){
    uint2 kr = *(const uint2*)(kb + (s0 + krow) * 32 + kcol);
    short4 vr;
    vr.x = (short)vb[(s0 + vs)     * 32 + vd];
    vr.y = (short)vb[(s0 + vs + 1) * 32 + vd];
    vr.z = (short)vb[(s0 + vs + 2) * 32 + vd];
    vr.w = (short)vb[(s0 + vs + 3) * 32 + vd];
    __syncthreads();
    *(uint2*)&ldsK[krow * 36 + kcol] = kr;
    *(short4*)&ldsV[vd * 36 + vs]   = vr;
    __syncthreads();

    s16x8 kf0 = *(const s16x8*)&ldsK[c * 36 + quad * 8];
    s16x8 kf1 = *(const s16x8*)&ldsK[(16 + c) * 36 + quad * 8];
    s16x8 vf0 = *(const s16x8*)&ldsV[c * 36 + quad * 8];
    s16x8 vf1 = *(const s16x8*)&ldsV[(16 + c) * 36 + quad * 8];

    f32x4 S0 = MFMA_BF16(qf0, kf0, zero);
    f32x4 S1 = MFMA_BF16(qf0, kf1, zero);
    #pragma unroll
    for (int r = 0; r < 4; r++){
      float p0 = __expf(S0[r]), p1 = __expf(S1[r]);
      l0[r] += p0 + p1;
      int prow = quad * 4 + r;
      ldsp[w][prow * 36 + c]      = f2b_trunc(p0);
      ldsp[w][prow * 36 + 16 + c] = f2b_trunc(p1);
    }
    s16x8 pf = *(const s16x8*)&ldsp[w][c * 36 + quad * 8];
    o00 = MFMA_BF16(pf, vf0, o00);
    o01 = MFMA_BF16(pf, vf1, o01);

    S0 = MFMA_BF16(qf1, kf0, zero);
    S1 = MFMA_BF16(qf1, kf1, zero);
    #pragma unroll
    for (int r = 0; r < 4; r++){
      float p0 = __expf(S0[r]), p1 = __expf(S1[r]);
      l1[r] += p0 + p1;
      int prow = quad * 4 + r;
      ldsp[w][prow * 36 + c]      = f2b_trunc(p0);
      ldsp[w][prow * 36 + 16 + c] = f2b_trunc(p1);
    }
    pf = *(const s16x8*)&ldsp[w][c * 36 + quad * 8];
    o10 = MFMA_BF16(pf, vf0, o10);
    o11 = MFMA_BF16(pf, vf1, o11);
  }

  #pragma unroll
  for (int r = 0; r < 4; r++){
    #pragma unroll
    for (int off = 8; off; off >>= 1){
      l0[r] += __shfl_xor(l0[r], off);
      l1[r] += __shfl_xor(l1[r], off);
    }
  }

  int ba = bah >> 3, hh = bah & 7;
  #pragma unroll
  for (int r = 0; r < 4; r++){
    int t0 = q0 + quad * 4 + r;
    float inv0 = 1.0f / l0[r], inv1 = 1.0f / l1[r];
    size_t base0 = ((size_t)(ba * 512 + t0)) * 256 + hh * 32;
    size_t base1 = base0 + 16 * 256;
    y[base0 + c]      = f2b(o00[r] * inv0);
    y[base0 + 16 + c] = f2b(o01[r] * inv0);
    y[base1 + c]      = f2b(o10[r] * inv1);
    y[base1 + 16 + c] = f2b(o11[r] * inv1);
  }
}

// ---------------- launch ----------------
extern "C" void kernel_launch(void* const* d_in, const int* in_sizes, int n_in,
                              void* d_out, int out_size, void* d_ws, size_t ws_size,
                              hipStream_t stream)
{
  const float* x      = (const float*)d_in[0];
  const float* ln1_w  = (const float*)d_in[1];
  const float* ln1_b  = (const float*)d_in[2];
  const float* qkv_w  = (const float*)d_in[3];
  const float* qkv_b  = (const float*)d_in[4];
  const float* proj_w = (const float*)d_in[5];
  const float* proj_b = (const float*)d_in[6];
  const float* ln2_w  = (const float*)d_in[7];
  const float* ln2_b  = (const float*)d_in[8];
  const float* fc_w   = (const float*)d_in[9];
  const float* fc_b   = (const float*)d_in[10];
  const float* fc2_w  = (const float*)d_in[11];
  const float* fc2_b  = (const float*)d_in[12];
  float* out = (float*)d_out;
  char* ws = (char*)d_ws;

  // ws layout (bytes):
  // [0,32M) xn | [32M,166M) q|k|v|y | [166M,200M) x2n | [200M,~201M) weights
  u16* xn   = (u16*)ws;
  u16* qb   = (u16*)(ws + (size_t)33554432);
  u16* kb   = qb + 16777216;
  u16* vb   = kb + 16777216;
  u16* yb   = vb + 16777216;
  u16* x2n  = (u16*)(ws + (size_t)173015040);
  u16* wqkvT  = (u16*)(ws + (size_t)206569472);
  u16* wprojT = wqkvT + 196608;
  u16* wfcT   = wprojT + 65536;
  u16* wfc2T  = wfcT + 262144;

  wconv_all<<<3072, 256, 0, stream>>>(qkv_w, wqkvT, proj_w, wprojT, fc_w, wfcT, fc2_w, wfc2T);

  ln_f32<<<16384, 256, 0, stream>>>(x, ln1_w, ln1_b, xn);
  gemm128<0,6><<<3072, 256, 0, stream>>>(xn, wqkvT, qkv_b, nullptr, qb, kb, vb, 768, 256);
  attn_kernel<<<4096, 256, 0, stream>>>(qb, kb, vb, yb);
  proj_ln<<<1024, 256, 0, stream>>>(yb, wprojT, proj_b, xn, ln2_w, ln2_b, x2n);
  ffn_fused<<<1024, 256, 0, stream>>>(x2n, wfcT, fc_b, wfc2T, fc2_b, out);
}

// Round 6
// 488.622 us; speedup vs baseline: 1.0996x; 1.0996x over previous
//
#include <hip/hip_runtime.h>

typedef unsigned short u16;
typedef __attribute__((ext_vector_type(8))) short s16x8;   // 8 bf16 in 4 VGPRs
typedef __attribute__((ext_vector_type(4))) float f32x4;

#define MFMA_BF16(a,b,c) __builtin_amdgcn_mfma_f32_16x16x32_bf16((a),(b),(c),0,0,0)

// async global->LDS, 16B per lane. LDS dest is wave-uniform base + lane*16;
// our staging layouts are lane-linear so per-lane pointer == base + lane*16.
#define GLL(gp, lp) __builtin_amdgcn_global_load_lds( \
    (const __attribute__((address_space(1))) void*)(gp), \
    (__attribute__((address_space(3))) void*)(lp), 16, 0, 0)

// counted-vmcnt barrier: wait for all but the newest N vmem ops, then s_barrier.
// asm memory clobber + sched_barrier(0) fence per guide rule #18.
#define PIPE_WAIT_BAR(N) do { \
  asm volatile("s_waitcnt vmcnt(" #N ")" ::: "memory"); \
  __builtin_amdgcn_sched_barrier(0); \
  __builtin_amdgcn_s_barrier(); \
  __builtin_amdgcn_sched_barrier(0); \
} while (0)

#define PIPE_BAR() do { \
  asm volatile("" ::: "memory"); \
  __builtin_amdgcn_sched_barrier(0); \
  __builtin_amdgcn_s_barrier(); \
  __builtin_amdgcn_sched_barrier(0); \
} while (0)

__device__ __forceinline__ float b2f(u16 s){
  union { unsigned u; float f; } v; v.u = ((unsigned)s) << 16; return v.f;
}
__device__ __forceinline__ u16 f2b(float x){
  union { float f; unsigned u; } v; v.f = x;
  unsigned u = v.u;
  return (u16)((u + 0x7FFFu + ((u >> 16) & 1u)) >> 16);   // round-to-nearest-even
}
__device__ __forceinline__ u16 f2b_trunc(float x){
  union { float f; unsigned u; } v; v.f = x;
  return (u16)(v.u >> 16);                                 // truncate (softmax-safe)
}

// exact-enough GELU: erf via Abramowitz-Stegun 7.1.26 (max abs err 1.5e-7,
// far below bf16 ulp) — ~12 VALU ops vs libm erff's ~60+.
__device__ __forceinline__ float gelu_fast(float v){
  float av = fabsf(v) * 0.70710678118654752f;
  float t  = __builtin_amdgcn_rcpf(1.0f + 0.3275911f * av);
  float p  = ((((1.061405429f * t - 1.453152027f) * t + 1.421413741f) * t
               - 0.284496736f) * t + 0.254829592f) * t;
  float erfa = 1.0f - p * __expf(-av * av);
  return 0.5f * v * (1.0f + copysignf(erfa, v));
}

// ---------------- all weight converts in one dispatch (f32 [K][N] -> bf16 [N][K]) ----------------
__global__ __launch_bounds__(256) void wconv_all(
    const float* __restrict__ w0, u16* __restrict__ t0,   // qkv  256x768
    const float* __restrict__ w1, u16* __restrict__ t1,   // proj 256x256
    const float* __restrict__ w2, u16* __restrict__ t2,   // fc   256x1024
    const float* __restrict__ w3, u16* __restrict__ t3)   // fc2  1024x256
{
  int bid = blockIdx.x;
  const float* w; u16* t; int K, N, base;
  if (bid < 768)        { w = w0; t = t0; K = 256;  N = 768;  base = bid; }
  else if (bid < 1024)  { w = w1; t = t1; K = 256;  N = 256;  base = bid - 768; }
  else if (bid < 2048)  { w = w2; t = t2; K = 256;  N = 1024; base = bid - 1024; }
  else                  { w = w3; t = t3; K = 1024; N = 256;  base = bid - 2048; }
  int idx = base * 256 + threadIdx.x;
  if (idx >= K * N) return;
  int k = idx / N, n = idx - k * N;
  t[(size_t)n * K + k] = f2b(w[idx]);
}

// ---------------- LayerNorm over C=256, one wave per row; f32 in -> bf16 out ----------------
__global__ __launch_bounds__(256) void ln_f32(const float* __restrict__ in,
    const float* __restrict__ gam, const float* __restrict__ bet, u16* __restrict__ out)
{
  int wv = threadIdx.x >> 6, lane = threadIdx.x & 63;
  size_t row = (size_t)blockIdx.x * 4 + wv;
  float4 u = *(const float4*)(in + row * 256 + lane * 4);
  float s  = u.x + u.y + u.z + u.w;
  float s2 = u.x*u.x + u.y*u.y + u.z*u.z + u.w*u.w;
  #pragma unroll
  for (int off = 32; off; off >>= 1){
    s  += __shfl_xor(s, off);
    s2 += __shfl_xor(s2, off);
  }
  float mean = s * (1.0f/256.0f);
  float var  = s2 * (1.0f/256.0f) - mean*mean;
  float rs   = rsqrtf(var + 1e-5f);
  int c = lane * 4;
  float4 g4 = *(const float4*)(gam + c);
  float4 b4 = *(const float4*)(bet + c);
  ushort4 o;
  o.x = f2b((u.x - mean)*rs*g4.x + b4.x);
  o.y = f2b((u.y - mean)*rs*g4.y + b4.y);
  o.z = f2b((u.z - mean)*rs*g4.z + b4.z);
  o.w = f2b((u.w - mean)*rs*g4.w + b4.w);
  *(ushort4*)(out + row * 256 + c) = o;
}

// ---------------- 128x128-tile bf16 MFMA GEMM, XCD-swizzled 1D grid ----------------
// DEPTH-3 global_load_lds pipeline (triple-buffered LDS, vmcnt(8) in-loop).
// Epilogue: LDS-staged chunks; readback stores full contiguous 128B lines.
// EPI 0: QKV scatter (+bias) -> o0=q (PRE-SCALED by 1/sqrt(32)), o1=k, o2=v, [bah][t][d] bf16
template<int EPI, int NT>
__global__ __launch_bounds__(256) void gemm128(
    const u16* __restrict__ A, const u16* __restrict__ Bt, const float* __restrict__ bias,
    const u16* __restrict__ res, void* __restrict__ o0v, u16* __restrict__ o1, u16* __restrict__ o2,
    int N, int K)
{
  __shared__ __align__(16) u16 lds[24576];
  int tid = threadIdx.x;
  int w = tid >> 6, lane = tid & 63;
  int quad = lane >> 4, c = lane & 15;
  int bid = blockIdx.x;
  int x = bid & 7, j = bid >> 3;
  int nt = j % NT, mt = (j / NT) * 8 + x;
  int wm = (w >> 1) * 64, wn = (w & 1) * 64;
  const u16* Abase = A + (size_t)mt * 128 * K;
  const u16* Bbase = Bt + (size_t)nt * 128 * K;
  int m0 = tid & 127, jj0 = tid >> 7;
  f32x4 zero = {0.f, 0.f, 0.f, 0.f};
  f32x4 acc[4][4];
  #pragma unroll
  for (int mi = 0; mi < 4; mi++)
    #pragma unroll
    for (int ni = 0; ni < 4; ni++) acc[mi][ni] = zero;

  auto stage = [&](int buf, int k0){
    u16* base = &lds[buf * 8192];
    GLL(Abase + (size_t)m0 * K + k0 + jj0 * 8,       &base[tid * 8]);
    GLL(Abase + (size_t)m0 * K + k0 + (jj0 + 2) * 8, &base[2048 + tid * 8]);
    GLL(Bbase + (size_t)m0 * K + k0 + jj0 * 8,       &base[4096 + tid * 8]);
    GLL(Bbase + (size_t)m0 * K + k0 + (jj0 + 2) * 8, &base[6144 + tid * 8]);
  };
  auto compute = [&](int cb){
    const u16* Lb = &lds[cb * 8192];
    s16x8 af[4], bfr[4];
    #pragma unroll
    for (int mi = 0; mi < 4; mi++)
      af[mi] = *(const s16x8*)&Lb[(quad * 128 + wm + mi * 16 + c) * 8];
    #pragma unroll
    for (int ni = 0; ni < 4; ni++)
      bfr[ni] = *(const s16x8*)&Lb[4096 + (quad * 128 + wn + ni * 16 + c) * 8];
    #pragma unroll
    for (int mi = 0; mi < 4; mi++)
      #pragma unroll
      for (int ni = 0; ni < 4; ni++)
        acc[mi][ni] = MFMA_BF16(af[mi], bfr[ni], acc[mi][ni]);
  };

  stage(0, 0); stage(1, 32); stage(2, 64);
  int cur = 0;
  int k0 = 0;
  for (; k0 + 96 < K; k0 += 32){
    PIPE_WAIT_BAR(8);
    compute(cur);
    PIPE_BAR();
    stage(cur, k0 + 96);
    cur = (cur == 2) ? 0 : cur + 1;
  }
  PIPE_WAIT_BAR(8); compute(cur); cur = (cur == 2) ? 0 : cur + 1;
  PIPE_WAIT_BAR(4); compute(cur); cur = (cur == 2) ? 0 : cur + 1;
  PIPE_WAIT_BAR(0); compute(cur);

  // LDS-staged coalesced epilogue (full 128B-line stores)
  const int LS  = 132;
  int rr = tid >> 3;
  int c7 = tid & 7;

  #pragma unroll
  for (int ch = 0; ch < 4; ch++){
    __syncthreads();
    if ((w >> 1) == (ch >> 1)){
      #pragma unroll
      for (int mi2 = 0; mi2 < 2; mi2++){
        int mi = (ch & 1) * 2 + mi2;
        #pragma unroll
        for (int ni = 0; ni < 4; ni++){
          int col = wn + ni * 16 + c;
          float bv = bias[nt * 128 + col];
          #pragma unroll
          for (int r = 0; r < 4; r++){
            int cr = mi2 * 16 + quad * 4 + r;
            float vv = acc[mi][ni][r] + bv;
            if (EPI == 0){
              int gcol = nt * 128 + col;
              if ((gcol >> 8) == 0) vv *= 0.17677669529663687f;   // q pre-scale
              lds[cr * LS + col] = f2b(vv);
            }
          }
        }
      }
    }
    __syncthreads();
    int row = mt * 128 + ch * 32 + rr;
    #pragma unroll
    for (int jj2 = 0; jj2 < 2; jj2++){
      int colL = c7 * 8 + jj2 * 64;
      uint4 val = *(const uint4*)&lds[rr * LS + colL];
      if (EPI == 0){
        int gcol = nt * 128 + colL;
        int which = gcol >> 8, ccc = gcol & 255;
        int hh = ccc >> 5, d = ccc & 31;
        int ba = row >> 9, t = row & 511;
        size_t idx = (((size_t)(ba * 8 + hh)) * 512 + t) * 32 + d;
        u16* dst = (which == 0) ? (u16*)o0v : ((which == 1) ? o1 : o2);
        *(uint4*)(dst + idx) = val;
      } else {
        *(uint4*)((u16*)o0v + (size_t)row * N + nt * 128 + colL) = val;
      }
    }
  }
}

// ---------------- fused FFN: out = x2n + (gelu(x2n@fc_w + fc_b) @ fc2_w + fc2_b) ----------------
// One block = 64 rows, 512 threads / 8 waves. Wave w owns out cols [32w,32w+32)
// (acc2[4][2]) and h cols [16w,16w+16) (acc1[4]); __launch_bounds__(512,4) caps
// VGPR at 128 -> 4 waves/SIMD (VGPR-bound: 2 blocks/CU, 16 waves/CU).
// LDS 48KB: x2n tile 32KB [0,32768)B (XOR-swizzled via pre-swizzled GLL source)
// + h chunk 16KB [32768,49152)B (64 rows x 128 cols bf16, swizzled).
// ROUND-5 BUG: lds was sized 40960B with hl at 32768 -> h rows 32-63 fell past
// the LDS allocation (DS ops beyond the block are dropped) -> absmax 0.617.
// h chunk is 64*128*2 = 16KB, NOT 8KB. Array restored to 24576 u16 = 49152B.
// Weights gathered from L2 (0.5MB each). h never hits global; residual read
// from LDS; f32 out bounced through LDS with per-instruction-contiguous stores.
__global__ __launch_bounds__(512, 4) void ffn_fused(
    const u16* __restrict__ x2n, const u16* __restrict__ fcT, const float* __restrict__ fcb,
    const u16* __restrict__ fc2T, const float* __restrict__ fc2b, float* __restrict__ out)
{
  __shared__ __align__(16) u16 lds[24576];             // 49152 B
  int tid = threadIdx.x;
  int w = tid >> 6, lane = tid & 63;
  int quad = lane >> 4, c = lane & 15;
  int mt = blockIdx.x;                                 // 64-row tile
  const u16* Abase = x2n + (size_t)mt * 64 * 256;
  char* ldsc = (char*)lds;                             // x2n, row stride 512B, XOR (row&7)<<4
  char* hl   = (char*)lds + 32768;                     // h, row stride 256B, XOR (row&15)<<4

  // ---- stage x2n swizzled: LDS byte ci*16 holds global (row*512 + (slot*16 ^ (row&7)<<4))
  #pragma unroll
  for (int i = 0; i < 4; i++){
    int ci = i * 512 + tid;
    int row = ci >> 5, slot = ci & 31;
    int glow = (slot * 16) ^ ((row & 7) << 4);
    GLL((const char*)Abase + row * 512 + glow, ldsc + ci * 16);
  }
  f32x4 zero = {0.f, 0.f, 0.f, 0.f};
  f32x4 acc2[4][2];
  #pragma unroll
  for (int mi = 0; mi < 4; mi++){ acc2[mi][0] = zero; acc2[mi][1] = zero; }
  PIPE_WAIT_BAR(0);

  for (int hc = 0; hc < 8; hc++){
    // ---- GEMM1: h cols [16w,16w+16) of chunk = x2n_tile @ fc_w[:, hc*128+16w ...]
    f32x4 acc1[4];
    #pragma unroll
    for (int mi = 0; mi < 4; mi++) acc1[mi] = zero;
    int n1 = hc * 128 + w * 16 + c;
    const u16* fb = fcT + (size_t)n1 * 256 + quad * 8;
    #pragma unroll
    for (int ks = 0; ks < 8; ks++){
      s16x8 bf1 = *(const s16x8*)(fb + ks * 32);
      #pragma unroll
      for (int mi = 0; mi < 4; mi++){
        int row = mi * 16 + c;
        int kb = (ks * 64 + quad * 16) ^ ((row & 7) << 4);
        s16x8 af = *(const s16x8*)(ldsc + row * 512 + kb);
        acc1[mi] = MFMA_BF16(af, bf1, acc1[mi]);
      }
    }
    __syncthreads();   // previous chunk's GEMM2 h-reads complete
    // ---- gelu -> bf16 h chunk (swizzled)
    {
      int colc = w * 16 + c;                           // chunk-local h col [0,128)
      float bv = fcb[hc * 128 + colc];
      #pragma unroll
      for (int mi = 0; mi < 4; mi++){
        #pragma unroll
        for (int r = 0; r < 4; r++){
          int row = mi * 16 + quad * 4 + r;
          int by = (colc * 2) ^ ((row & 15) << 4);
          *(u16*)(hl + row * 256 + by) = f2b(gelu_fast(acc1[mi][r] + bv));
        }
      }
    }
    __syncthreads();   // h visible to all
    // ---- GEMM2 partial: acc2 += h_chunk @ fc2_w[hc*128:+128, cols 32w..32w+32)
    #pragma unroll
    for (int ks = 0; ks < 4; ks++){
      s16x8 ha[4], bf2[2];
      #pragma unroll
      for (int ni = 0; ni < 2; ni++){
        int n = w * 32 + ni * 16 + c;
        bf2[ni] = *(const s16x8*)(fc2T + (size_t)n * 1024 + hc * 128 + ks * 32 + quad * 8);
      }
      #pragma unroll
      for (int mi = 0; mi < 4; mi++){
        int row = mi * 16 + c;
        int kb = (ks * 64 + quad * 16) ^ ((row & 15) << 4);
        ha[mi] = *(const s16x8*)(hl + row * 256 + kb);
      }
      #pragma unroll
      for (int mi = 0; mi < 4; mi++){
        acc2[mi][0] = MFMA_BF16(ha[mi], bf2[0], acc2[mi][0]);
        acc2[mi][1] = MFMA_BF16(ha[mi], bf2[1], acc2[mi][1]);
      }
    }
  }

  // ---- fold bias + residual (x2n from LDS) into acc2
  #pragma unroll
  for (int ni = 0; ni < 2; ni++){
    int col = w * 32 + ni * 16 + c;
    float bv = fc2b[col];
    #pragma unroll
    for (int mi = 0; mi < 4; mi++){
      #pragma unroll
      for (int r = 0; r < 4; r++){
        int row = mi * 16 + quad * 4 + r;
        int by = (col * 2) ^ ((row & 7) << 4);
        u16 xv = *(const u16*)(ldsc + row * 512 + by);
        acc2[mi][ni][r] += bv + b2f(xv);
      }
    }
  }
  __syncthreads();   // all LDS reads done before bounce overwrite

  // ---- f32 bounce: 4 chunks of 16 rows (mi == ch); per-instruction-contiguous
  // 512B stores (lanes 0..31 cover cols [0,128) then [128,256)).
  float* ldsF = (float*)lds;
  const int LSO = 260;
  int orow = tid >> 5, oc = (tid & 31) * 4;
  #pragma unroll
  for (int ch = 0; ch < 4; ch++){
    #pragma unroll
    for (int ni = 0; ni < 2; ni++){
      #pragma unroll
      for (int r = 0; r < 4; r++){
        int crow = quad * 4 + r;
        ldsF[crow * LSO + w * 32 + ni * 16 + c] = acc2[ch][ni][r];
      }
    }
    __syncthreads();
    size_t rb = ((size_t)mt * 64 + ch * 16 + orow) * 256;
    *(float4*)(out + rb + oc)       = *(const float4*)&ldsF[orow * LSO + oc];
    *(float4*)(out + rb + oc + 128) = *(const float4*)&ldsF[orow * LSO + oc + 128];
    __syncthreads();
  }
}

// ---------------- fused proj GEMM + residual + LayerNorm2 -> x2n ----------------
// 2-phase global_load_lds pipeline (5 loads/stage -> vmcnt(5)).
__global__ __launch_bounds__(256) void proj_ln(
    const u16* __restrict__ A, const u16* __restrict__ Bt, const float* __restrict__ bias,
    const u16* __restrict__ res, const float* __restrict__ gam, const float* __restrict__ bet,
    u16* __restrict__ x2n)
{
  __shared__ __align__(16) u16 lds[20480];
  int tid = threadIdx.x;
  int w = tid >> 6, lane = tid & 63;
  int quad = lane >> 4, c = lane & 15;
  int mt = blockIdx.x;
  int wn = w * 64;
  const u16* Abase = A + (size_t)mt * 64 * 256;
  int an = tid & 63, aj = tid >> 6;
  f32x4 zero = {0.f, 0.f, 0.f, 0.f};
  f32x4 acc[4][4];
  #pragma unroll
  for (int mi = 0; mi < 4; mi++)
    #pragma unroll
    for (int ni = 0; ni < 4; ni++) acc[mi][ni] = zero;

  auto stage = [&](int buf, int k0){
    u16* base = &lds[buf * 10240];
    GLL(Abase + (size_t)an * 256 + k0 + aj * 8, &base[tid * 8]);
    #pragma unroll
    for (int i = 0; i < 4; i++){
      int ci = tid + i * 256;
      int n = ci & 255, jjb = ci >> 8;
      GLL(Bt + (size_t)n * 256 + k0 + jjb * 8, &base[2048 + ci * 8]);
    }
  };
  auto compute = [&](int cb){
    const u16* base = &lds[cb * 10240];
    s16x8 af[4], bfr[4];
    #pragma unroll
    for (int mi = 0; mi < 4; mi++)
      af[mi] = *(const s16x8*)&base[(quad * 64 + mi * 16 + c) * 8];
    #pragma unroll
    for (int ni = 0; ni < 4; ni++)
      bfr[ni] = *(const s16x8*)&base[2048 + (quad * 256 + wn + ni * 16 + c) * 8];
    #pragma unroll
    for (int mi = 0; mi < 4; mi++)
      #pragma unroll
      for (int ni = 0; ni < 4; ni++)
        acc[mi][ni] = MFMA_BF16(af[mi], bfr[ni], acc[mi][ni]);
  };

  stage(0, 0);
  int cur = 0;
  for (int k0 = 32; k0 < 256; k0 += 32){
    stage(cur ^ 1, k0);
    PIPE_WAIT_BAR(5);
    compute(cur);
    PIPE_BAR();
    cur ^= 1;
  }
  PIPE_WAIT_BAR(0);
  compute(cur);
  __syncthreads();

  #pragma unroll
  for (int ni = 0; ni < 4; ni++){
    int col = wn + ni * 16 + c;
    float bv = bias[col];
    #pragma unroll
    for (int mi = 0; mi < 4; mi++){
      #pragma unroll
      for (int r = 0; r < 4; r++){
        int rowL = mi * 16 + quad * 4 + r;
        size_t gidx = ((size_t)mt * 64 + rowL) * 256 + col;
        lds[rowL * 264 + col] = f2b(acc[mi][ni][r] + bv + b2f(res[gidx]));
      }
    }
  }
  __syncthreads();

  int rowL = tid >> 2, part = (tid & 3) * 64;
  float s = 0.f, s2 = 0.f;
  #pragma unroll
  for (int i = 0; i < 16; i++){
    ushort4 u = *(const ushort4*)&lds[rowL * 264 + part + i * 4];
    float v0 = b2f(u.x), v1 = b2f(u.y), v2 = b2f(u.z), v3 = b2f(u.w);
    s  += v0 + v1 + v2 + v3;
    s2 += v0*v0 + v1*v1 + v2*v2 + v3*v3;
  }
  s  += __shfl_xor(s, 1);  s  += __shfl_xor(s, 2);
  s2 += __shfl_xor(s2, 1); s2 += __shfl_xor(s2, 2);
  float mean = s * (1.0f/256.0f);
  float var  = s2 * (1.0f/256.0f) - mean*mean;
  float rs   = rsqrtf(var + 1e-5f);
  size_t orow = ((size_t)mt * 64 + rowL) * 256;
  #pragma unroll
  for (int i = 0; i < 16; i++){
    int col = part + i * 4;
    ushort4 u = *(const ushort4*)&lds[rowL * 264 + col];
    float4 g4 = *(const float4*)(gam + col);
    float4 b4 = *(const float4*)(bet + col);
    ushort4 o;
    o.x = f2b((b2f(u.x) - mean)*rs*g4.x + b4.x);
    o.y = f2b((b2f(u.y) - mean)*rs*g4.y + b4.y);
    o.z = f2b((b2f(u.z) - mean)*rs*g4.z + b4.z);
    o.w = f2b((b2f(u.w) - mean)*rs*g4.w + b4.w);
    *(ushort4*)(x2n + orow + col) = o;
  }
}

// ---------------- flash attention, no-max softmax; XCD-swizzled 1D grid ----------------
__global__ __launch_bounds__(256) void attn_kernel(const u16* __restrict__ q,
    const u16* __restrict__ k, const u16* __restrict__ v, u16* __restrict__ y)
{
  __shared__ __align__(16) u16 ldsK[32 * 36];    // [s][d], row stride 36
  __shared__ __align__(16) u16 ldsV[32 * 36];    // [d][s], row stride 36
  __shared__ __align__(16) u16 ldsp[4][16 * 36]; // per-wave P [prow][s], stride 36
  int tid = threadIdx.x;
  int w = tid >> 6, lane = tid & 63;
  int quad = lane >> 4, c = lane & 15;
  int bid = blockIdx.x;
  int x = bid & 7, j = bid >> 3;
  int qt = j & 3, bah = (j >> 2) * 8 + x;
  int q0 = qt * 128 + w * 32;
  const u16* qb = q + (size_t)bah * 16384;
  const u16* kb = k + (size_t)bah * 16384;
  const u16* vb = v + (size_t)bah * 16384;
  int krow = tid >> 3, kcol = (tid & 7) * 4;     // K staging: uint2 per thread
  int vd = tid & 31,  vs = (tid >> 5) * 4;       // V staging: 4 strided u16 -> b64

  s16x8 qf0 = *(const s16x8*)(qb + (q0 + c) * 32 + quad * 8);
  s16x8 qf1 = *(const s16x8*)(qb + (q0 + 16 + c) * 32 + quad * 8);
  float l0[4] = {0.f,0.f,0.f,0.f}, l1[4] = {0.f,0.f,0.f,0.f};
  f32x4 o00 = {0,0,0,0}, o01 = {0,0,0,0}, o10 = {0,0,0,0}, o11 = {0,0,0,0};
  f32x4 zero = {0,0,0,0};

  for (int s0 = 0; s0 < 512; s0 += 32){
    uint2 kr = *(const uint2*)(kb + (s0 + krow) * 32 + kcol);
    short4 vr;
    vr.x = (short)vb[(s0 + vs)     * 32 + vd];
    vr.y = (short)vb[(s0 + vs + 1) * 32 + vd];
    vr.z = (short)vb[(s0 + vs + 2) * 32 + vd];
    vr.w = (short)vb[(s0 + vs + 3) * 32 + vd];
    __syncthreads();
    *(uint2*)&ldsK[krow * 36 + kcol] = kr;
    *(short4*)&ldsV[vd * 36 + vs]   = vr;
    __syncthreads();

    s16x8 kf0 = *(const s16x8*)&ldsK[c * 36 + quad * 8];
    s16x8 kf1 = *(const s16x8*)&ldsK[(16 + c) * 36 + quad * 8];
    s16x8 vf0 = *(const s16x8*)&ldsV[c * 36 + quad * 8];
    s16x8 vf1 = *(const s16x8*)&ldsV[(16 + c) * 36 + quad * 8];

    f32x4 S0 = MFMA_BF16(qf0, kf0, zero);
    f32x4 S1 = MFMA_BF16(qf0, kf1, zero);
    #pragma unroll
    for (int r = 0; r < 4; r++){
      float p0 = __expf(S0[r]), p1 = __expf(S1[r]);
      l0[r] += p0 + p1;
      int prow = quad * 4 + r;
      ldsp[w][prow * 36 + c]      = f2b_trunc(p0);
      ldsp[w][prow * 36 + 16 + c] = f2b_trunc(p1);
    }
    s16x8 pf = *(const s16x8*)&ldsp[w][c * 36 + quad * 8];
    o00 = MFMA_BF16(pf, vf0, o00);
    o01 = MFMA_BF16(pf, vf1, o01);

    S0 = MFMA_BF16(qf1, kf0, zero);
    S1 = MFMA_BF16(qf1, kf1, zero);
    #pragma unroll
    for (int r = 0; r < 4; r++){
      float p0 = __expf(S0[r]), p1 = __expf(S1[r]);
      l1[r] += p0 + p1;
      int prow = quad * 4 + r;
      ldsp[w][prow * 36 + c]      = f2b_trunc(p0);
      ldsp[w][prow * 36 + 16 + c] = f2b_trunc(p1);
    }
    pf = *(const s16x8*)&ldsp[w][c * 36 + quad * 8];
    o10 = MFMA_BF16(pf, vf0, o10);
    o11 = MFMA_BF16(pf, vf1, o11);
  }

  #pragma unroll
  for (int r = 0; r < 4; r++){
    #pragma unroll
    for (int off = 8; off; off >>= 1){
      l0[r] += __shfl_xor(l0[r], off);
      l1[r] += __shfl_xor(l1[r], off);
    }
  }

  int ba = bah >> 3, hh = bah & 7;
  #pragma unroll
  for (int r = 0; r < 4; r++){
    int t0 = q0 + quad * 4 + r;
    float inv0 = 1.0f / l0[r], inv1 = 1.0f / l1[r];
    size_t base0 = ((size_t)(ba * 512 + t0)) * 256 + hh * 32;
    size_t base1 = base0 + 16 * 256;
    y[base0 + c]      = f2b(o00[r] * inv0);
    y[base0 + 16 + c] = f2b(o01[r] * inv0);
    y[base1 + c]      = f2b(o10[r] * inv1);
    y[base1 + 16 + c] = f2b(o11[r] * inv1);
  }
}

// ---------------- launch ----------------
extern "C" void kernel_launch(void* const* d_in, const int* in_sizes, int n_in,
                              void* d_out, int out_size, void* d_ws, size_t ws_size,
                              hipStream_t stream)
{
  const float* x      = (const float*)d_in[0];
  const float* ln1_w  = (const float*)d_in[1];
  const float* ln1_b  = (const float*)d_in[2];
  const float* qkv_w  = (const float*)d_in[3];
  const float* qkv_b  = (const float*)d_in[4];
  const float* proj_w = (const float*)d_in[5];
  const float* proj_b = (const float*)d_in[6];
  const float* ln2_w  = (const float*)d_in[7];
  const float* ln2_b  = (const float*)d_in[8];
  const float* fc_w   = (const float*)d_in[9];
  const float* fc_b   = (const float*)d_in[10];
  const float* fc2_w  = (const float*)d_in[11];
  const float* fc2_b  = (const float*)d_in[12];
  float* out = (float*)d_out;
  char* ws = (char*)d_ws;

  // ws layout (bytes):
  // [0,32M) xn | [32M,166M) q|k|v|y | [166M,200M) x2n | [200M,~201M) weights
  u16* xn   = (u16*)ws;
  u16* qb   = (u16*)(ws + (size_t)33554432);
  u16* kb   = qb + 16777216;
  u16* vb   = kb + 16777216;
  u16* yb   = vb + 16777216;
  u16* x2n  = (u16*)(ws + (size_t)173015040);
  u16* wqkvT  = (u16*)(ws + (size_t)206569472);
  u16* wprojT = wqkvT + 196608;
  u16* wfcT   = wprojT + 65536;
  u16* wfc2T  = wfcT + 262144;

  wconv_all<<<3072, 256, 0, stream>>>(qkv_w, wqkvT, proj_w, wprojT, fc_w, wfcT, fc2_w, wfc2T);

  ln_f32<<<16384, 256, 0, stream>>>(x, ln1_w, ln1_b, xn);
  gemm128<0,6><<<3072, 256, 0, stream>>>(xn, wqkvT, qkv_b, nullptr, qb, kb, vb, 768, 256);
  attn_kernel<<<4096, 256, 0, stream>>>(qb, kb, vb, yb);
  proj_ln<<<1024, 256, 0, stream>>>(yb, wprojT, proj_b, xn, ln2_w, ln2_b, x2n);
  ffn_fused<<<1024, 512, 0, stream>>>(x2n, wfcT, fc_b, wfc2T, fc2_b, out);
}

// Round 8
// 471.668 us; speedup vs baseline: 1.1391x; 1.0359x over previous
//
#include <hip/hip_runtime.h>

typedef unsigned short u16;
typedef __attribute__((ext_vector_type(8))) short s16x8;   // 8 bf16 in 4 VGPRs
typedef __attribute__((ext_vector_type(4))) float f32x4;

#define MFMA_BF16(a,b,c) __builtin_amdgcn_mfma_f32_16x16x32_bf16((a),(b),(c),0,0,0)

// async global->LDS, 16B per lane. LDS dest is wave-uniform base + lane*16;
// our staging layouts are lane-linear so per-lane pointer == base + lane*16.
#define GLL(gp, lp) __builtin_amdgcn_global_load_lds( \
    (const __attribute__((address_space(1))) void*)(gp), \
    (__attribute__((address_space(3))) void*)(lp), 16, 0, 0)

// counted-vmcnt barrier: wait for all but the newest N vmem ops, then s_barrier.
// asm memory clobber + sched_barrier(0) fence per guide rule #18.
#define PIPE_WAIT_BAR(N) do { \
  asm volatile("s_waitcnt vmcnt(" #N ")" ::: "memory"); \
  __builtin_amdgcn_sched_barrier(0); \
  __builtin_amdgcn_s_barrier(); \
  __builtin_amdgcn_sched_barrier(0); \
} while (0)

#define PIPE_BAR() do { \
  asm volatile("" ::: "memory"); \
  __builtin_amdgcn_sched_barrier(0); \
  __builtin_amdgcn_s_barrier(); \
  __builtin_amdgcn_sched_barrier(0); \
} while (0)

__device__ __forceinline__ float b2f(u16 s){
  union { unsigned u; float f; } v; v.u = ((unsigned)s) << 16; return v.f;
}
__device__ __forceinline__ u16 f2b(float x){
  union { float f; unsigned u; } v; v.f = x;
  unsigned u = v.u;
  return (u16)((u + 0x7FFFu + ((u >> 16) & 1u)) >> 16);   // round-to-nearest-even
}
__device__ __forceinline__ u16 f2b_trunc(float x){
  union { float f; unsigned u; } v; v.f = x;
  return (u16)(v.u >> 16);                                 // truncate (softmax-safe)
}

// exact-enough GELU: erf via Abramowitz-Stegun 7.1.26 (max abs err 1.5e-7,
// far below bf16 ulp) — ~12 VALU ops vs libm erff's ~60+.
__device__ __forceinline__ float gelu_fast(float v){
  float av = fabsf(v) * 0.70710678118654752f;
  float t  = __builtin_amdgcn_rcpf(1.0f + 0.3275911f * av);
  float p  = ((((1.061405429f * t - 1.453152027f) * t + 1.421413741f) * t
               - 0.284496736f) * t + 0.254829592f) * t;
  float erfa = 1.0f - p * __expf(-av * av);
  return 0.5f * v * (1.0f + copysignf(erfa, v));
}

// ---------------- all weight converts in one dispatch (f32 [K][N] -> bf16 [N][K]) ----------------
__global__ __launch_bounds__(256) void wconv_all(
    const float* __restrict__ w0, u16* __restrict__ t0,   // qkv  256x768
    const float* __restrict__ w1, u16* __restrict__ t1,   // proj 256x256
    const float* __restrict__ w2, u16* __restrict__ t2,   // fc   256x1024
    const float* __restrict__ w3, u16* __restrict__ t3)   // fc2  1024x256
{
  int bid = blockIdx.x;
  const float* w; u16* t; int K, N, base;
  if (bid < 768)        { w = w0; t = t0; K = 256;  N = 768;  base = bid; }
  else if (bid < 1024)  { w = w1; t = t1; K = 256;  N = 256;  base = bid - 768; }
  else if (bid < 2048)  { w = w2; t = t2; K = 256;  N = 1024; base = bid - 1024; }
  else                  { w = w3; t = t3; K = 1024; N = 256;  base = bid - 2048; }
  int idx = base * 256 + threadIdx.x;
  if (idx >= K * N) return;
  int k = idx / N, n = idx - k * N;
  t[(size_t)n * K + k] = f2b(w[idx]);
}

// ---------------- LayerNorm over C=256, one wave per row; f32 in -> bf16 out ----------------
__global__ __launch_bounds__(256) void ln_f32(const float* __restrict__ in,
    const float* __restrict__ gam, const float* __restrict__ bet, u16* __restrict__ out)
{
  int wv = threadIdx.x >> 6, lane = threadIdx.x & 63;
  size_t row = (size_t)blockIdx.x * 4 + wv;
  float4 u = *(const float4*)(in + row * 256 + lane * 4);
  float s  = u.x + u.y + u.z + u.w;
  float s2 = u.x*u.x + u.y*u.y + u.z*u.z + u.w*u.w;
  #pragma unroll
  for (int off = 32; off; off >>= 1){
    s  += __shfl_xor(s, off);
    s2 += __shfl_xor(s2, off);
  }
  float mean = s * (1.0f/256.0f);
  float var  = s2 * (1.0f/256.0f) - mean*mean;
  float rs   = rsqrtf(var + 1e-5f);
  int c = lane * 4;
  float4 g4 = *(const float4*)(gam + c);
  float4 b4 = *(const float4*)(bet + c);
  ushort4 o;
  o.x = f2b((u.x - mean)*rs*g4.x + b4.x);
  o.y = f2b((u.y - mean)*rs*g4.y + b4.y);
  o.z = f2b((u.z - mean)*rs*g4.z + b4.z);
  o.w = f2b((u.w - mean)*rs*g4.w + b4.w);
  *(ushort4*)(out + row * 256 + c) = o;
}

// ---------------- 128x128-tile bf16 MFMA GEMM, XCD-swizzled 1D grid ----------------
// DEPTH-3 global_load_lds pipeline (triple-buffered LDS, vmcnt(8) in-loop).
// Epilogue: LDS-staged chunks; readback stores full contiguous 128B lines.
// EPI 0: QKV scatter (+bias) -> o0=q (PRE-SCALED by 1/sqrt(32)), o1=k, o2=v, [bah][t][d] bf16
template<int EPI, int NT>
__global__ __launch_bounds__(256) void gemm128(
    const u16* __restrict__ A, const u16* __restrict__ Bt, const float* __restrict__ bias,
    const u16* __restrict__ res, void* __restrict__ o0v, u16* __restrict__ o1, u16* __restrict__ o2,
    int N, int K)
{
  __shared__ __align__(16) u16 lds[24576];
  int tid = threadIdx.x;
  int w = tid >> 6, lane = tid & 63;
  int quad = lane >> 4, c = lane & 15;
  int bid = blockIdx.x;
  int x = bid & 7, j = bid >> 3;
  int nt = j % NT, mt = (j / NT) * 8 + x;
  int wm = (w >> 1) * 64, wn = (w & 1) * 64;
  const u16* Abase = A + (size_t)mt * 128 * K;
  const u16* Bbase = Bt + (size_t)nt * 128 * K;
  int m0 = tid & 127, jj0 = tid >> 7;
  f32x4 zero = {0.f, 0.f, 0.f, 0.f};
  f32x4 acc[4][4];
  #pragma unroll
  for (int mi = 0; mi < 4; mi++)
    #pragma unroll
    for (int ni = 0; ni < 4; ni++) acc[mi][ni] = zero;

  auto stage = [&](int buf, int k0){
    u16* base = &lds[buf * 8192];
    GLL(Abase + (size_t)m0 * K + k0 + jj0 * 8,       &base[tid * 8]);
    GLL(Abase + (size_t)m0 * K + k0 + (jj0 + 2) * 8, &base[2048 + tid * 8]);
    GLL(Bbase + (size_t)m0 * K + k0 + jj0 * 8,       &base[4096 + tid * 8]);
    GLL(Bbase + (size_t)m0 * K + k0 + (jj0 + 2) * 8, &base[6144 + tid * 8]);
  };
  auto compute = [&](int cb){
    const u16* Lb = &lds[cb * 8192];
    s16x8 af[4], bfr[4];
    #pragma unroll
    for (int mi = 0; mi < 4; mi++)
      af[mi] = *(const s16x8*)&Lb[(quad * 128 + wm + mi * 16 + c) * 8];
    #pragma unroll
    for (int ni = 0; ni < 4; ni++)
      bfr[ni] = *(const s16x8*)&Lb[4096 + (quad * 128 + wn + ni * 16 + c) * 8];
    #pragma unroll
    for (int mi = 0; mi < 4; mi++)
      #pragma unroll
      for (int ni = 0; ni < 4; ni++)
        acc[mi][ni] = MFMA_BF16(af[mi], bfr[ni], acc[mi][ni]);
  };

  stage(0, 0); stage(1, 32); stage(2, 64);
  int cur = 0;
  int k0 = 0;
  for (; k0 + 96 < K; k0 += 32){
    PIPE_WAIT_BAR(8);
    compute(cur);
    PIPE_BAR();
    stage(cur, k0 + 96);
    cur = (cur == 2) ? 0 : cur + 1;
  }
  PIPE_WAIT_BAR(8); compute(cur); cur = (cur == 2) ? 0 : cur + 1;
  PIPE_WAIT_BAR(4); compute(cur); cur = (cur == 2) ? 0 : cur + 1;
  PIPE_WAIT_BAR(0); compute(cur);

  // LDS-staged coalesced epilogue (full 128B-line stores)
  const int LS  = 132;
  int rr = tid >> 3;
  int c7 = tid & 7;

  #pragma unroll
  for (int ch = 0; ch < 4; ch++){
    __syncthreads();
    if ((w >> 1) == (ch >> 1)){
      #pragma unroll
      for (int mi2 = 0; mi2 < 2; mi2++){
        int mi = (ch & 1) * 2 + mi2;
        #pragma unroll
        for (int ni = 0; ni < 4; ni++){
          int col = wn + ni * 16 + c;
          float bv = bias[nt * 128 + col];
          #pragma unroll
          for (int r = 0; r < 4; r++){
            int cr = mi2 * 16 + quad * 4 + r;
            float vv = acc[mi][ni][r] + bv;
            if (EPI == 0){
              int gcol = nt * 128 + col;
              if ((gcol >> 8) == 0) vv *= 0.17677669529663687f;   // q pre-scale
              lds[cr * LS + col] = f2b(vv);
            }
          }
        }
      }
    }
    __syncthreads();
    int row = mt * 128 + ch * 32 + rr;
    #pragma unroll
    for (int jj2 = 0; jj2 < 2; jj2++){
      int colL = c7 * 8 + jj2 * 64;
      uint4 val = *(const uint4*)&lds[rr * LS + colL];
      if (EPI == 0){
        int gcol = nt * 128 + colL;
        int which = gcol >> 8, ccc = gcol & 255;
        int hh = ccc >> 5, d = ccc & 31;
        int ba = row >> 9, t = row & 511;
        size_t idx = (((size_t)(ba * 8 + hh)) * 512 + t) * 32 + d;
        u16* dst = (which == 0) ? (u16*)o0v : ((which == 1) ? o1 : o2);
        *(uint4*)(dst + idx) = val;
      } else {
        *(uint4*)((u16*)o0v + (size_t)row * N + nt * 128 + colL) = val;
      }
    }
  }
}

// ---------------- fused FFN: out = x2n + (gelu(x2n@fc_w + fc_b) @ fc2_w + fc2_b) ----------------
// One block = 64 rows, 512 threads / 8 waves. Round-6 post-mortem: serial
// phases (GEMM1 | gelu | GEMM2, 24 barriers) left MfmaUtil+VALU at 48%.
// Round-7 restructure:
//  (a) h double-buffered (2x16KB): iteration hc does GEMM1(hc+1)->gelu->h[b^1]
//      AND GEMM2(hc) reading h[b] in ONE barrier region (1 barrier/chunk, 9
//      total) -> GELU VALU co-schedules with GEMM2 MFMA (separate pipes).
//  (b) GEMM1 uses SWAPPED operands MFMA(w_frag, x2n_frag): same loads (A/B
//      fragment layouts are symmetric), transposed C -> each lane holds 4
//      consecutive h-cols at one row -> gelu packs into ONE short4 b64 store
//      (4 stores/chunk vs 16 scalar) and bias is a single float4 load.
// LDS 64KB: x2n 32KB [0,32K) | h0 [32K,48K) | h1 [48K,64K). 2 blocks/CU.
// Weights gathered from L2 (0.5MB each); h never hits global; residual from LDS.
__global__ __launch_bounds__(512, 4) void ffn_fused(
    const u16* __restrict__ x2n, const u16* __restrict__ fcT, const float* __restrict__ fcb,
    const u16* __restrict__ fc2T, const float* __restrict__ fc2b, float* __restrict__ out)
{
  __shared__ __align__(16) u16 lds[32768];             // 65536 B
  int tid = threadIdx.x;
  int w = tid >> 6, lane = tid & 63;
  int quad = lane >> 4, c = lane & 15;
  int mt = blockIdx.x;                                 // 64-row tile
  const u16* Abase = x2n + (size_t)mt * 64 * 256;
  char* ldsc = (char*)lds;                             // x2n, row stride 512B, XOR (row&7)<<4
  char* h0   = (char*)lds + 32768;                     // h bufs, row stride 256B, XOR (row&15)<<4
  char* h1   = (char*)lds + 49152;

  // ---- stage x2n swizzled: LDS byte ci*16 holds global (row*512 + (slot*16 ^ (row&7)<<4))
  #pragma unroll
  for (int i = 0; i < 4; i++){
    int ci = i * 512 + tid;
    int row = ci >> 5, slot = ci & 31;
    int glow = (slot * 16) ^ ((row & 7) << 4);
    GLL((const char*)Abase + row * 512 + glow, ldsc + ci * 16);
  }
  f32x4 zero = {0.f, 0.f, 0.f, 0.f};
  f32x4 acc2[4][2];
  #pragma unroll
  for (int mi = 0; mi < 4; mi++){ acc2[mi][0] = zero; acc2[mi][1] = zero; }
  PIPE_WAIT_BAR(0);

  // GEMM1 for chunk hcx -> gelu -> packed b64 stores into hw.
  // Swapped MFMA(bf1, af): lane (quad,c) holds h[n = w*16+quad*4+r][m = mi*16+c]
  // transposed -> 4 consecutive n at fixed m.
  auto gemm1 = [&](int hcx, char* hw){
    f32x4 acc1[4];
    #pragma unroll
    for (int mi = 0; mi < 4; mi++) acc1[mi] = zero;
    const u16* fb = fcT + (size_t)(hcx * 128 + w * 16 + c) * 256 + quad * 8;
    #pragma unroll
    for (int ks = 0; ks < 8; ks++){
      s16x8 bf1 = *(const s16x8*)(fb + ks * 32);
      #pragma unroll
      for (int mi = 0; mi < 4; mi++){
        int row = mi * 16 + c;
        int kb = (ks * 64 + quad * 16) ^ ((row & 7) << 4);
        s16x8 af = *(const s16x8*)(ldsc + row * 512 + kb);
        acc1[mi] = MFMA_BF16(bf1, af, acc1[mi]);      // swapped: C = w^T-rows x m-cols
      }
    }
    float4 bb = *(const float4*)(fcb + hcx * 128 + w * 16 + quad * 4);
    #pragma unroll
    for (int mi = 0; mi < 4; mi++){
      int m = mi * 16 + c;
      short4 pk;
      pk.x = (short)f2b(gelu_fast(acc1[mi][0] + bb.x));
      pk.y = (short)f2b(gelu_fast(acc1[mi][1] + bb.y));
      pk.z = (short)f2b(gelu_fast(acc1[mi][2] + bb.z));
      pk.w = (short)f2b(gelu_fast(acc1[mi][3] + bb.w));
      int by = (w * 32 + quad * 8) ^ ((m & 15) << 4);
      *(short4*)(hw + m * 256 + by) = pk;
    }
  };
  // GEMM2 partial for chunk hcx reading hr: acc2 += h_chunk @ fc2_w slice.
  auto gemm2 = [&](int hcx, const char* hr){
    #pragma unroll
    for (int ks = 0; ks < 4; ks++){
      s16x8 bf2[2];
      #pragma unroll
      for (int ni = 0; ni < 2; ni++){
        int n = w * 32 + ni * 16 + c;
        bf2[ni] = *(const s16x8*)(fc2T + (size_t)n * 1024 + hcx * 128 + ks * 32 + quad * 8);
      }
      #pragma unroll
      for (int mi = 0; mi < 4; mi++){
        int m = mi * 16 + c;
        int kb = (ks * 64 + quad * 16) ^ ((m & 15) << 4);
        s16x8 ha = *(const s16x8*)(hr + m * 256 + kb);
        acc2[mi][0] = MFMA_BF16(ha, bf2[0], acc2[mi][0]);
        acc2[mi][1] = MFMA_BF16(ha, bf2[1], acc2[mi][1]);
      }
    }
  };

  gemm1(0, h0);
  __syncthreads();
  for (int hc = 0; hc < 8; hc++){
    const char* hr = (hc & 1) ? h1 : h0;
    char* hw       = (hc & 1) ? h0 : h1;
    if (hc < 7) gemm1(hc + 1, hw);   // writes h[b^1]; gelu VALU overlaps GEMM2 MFMA
    gemm2(hc, hr);                   // reads h[b]
    __syncthreads();                 // hw visible; hr reads done before overwrite
  }

  // ---- fold bias + residual (x2n from LDS) into acc2
  #pragma unroll
  for (int ni = 0; ni < 2; ni++){
    int col = w * 32 + ni * 16 + c;
    float bv = fc2b[col];
    #pragma unroll
    for (int mi = 0; mi < 4; mi++){
      #pragma unroll
      for (int r = 0; r < 4; r++){
        int row = mi * 16 + quad * 4 + r;
        int by = (col * 2) ^ ((row & 7) << 4);
        u16 xv = *(const u16*)(ldsc + row * 512 + by);
        acc2[mi][ni][r] += bv + b2f(xv);
      }
    }
  }
  __syncthreads();   // all LDS reads done before bounce overwrite

  // ---- f32 bounce: 4 chunks of 16 rows (mi == ch); per-instruction-contiguous
  // 512B stores (lanes 0..31 cover cols [0,128) then [128,256)).
  float* ldsF = (float*)lds;
  const int LSO = 260;
  int orow = tid >> 5, oc = (tid & 31) * 4;
  #pragma unroll
  for (int ch = 0; ch < 4; ch++){
    #pragma unroll
    for (int ni = 0; ni < 2; ni++){
      #pragma unroll
      for (int r = 0; r < 4; r++){
        int crow = quad * 4 + r;
        ldsF[crow * LSO + w * 32 + ni * 16 + c] = acc2[ch][ni][r];
      }
    }
    __syncthreads();
    size_t rb = ((size_t)mt * 64 + ch * 16 + orow) * 256;
    *(float4*)(out + rb + oc)       = *(const float4*)&ldsF[orow * LSO + oc];
    *(float4*)(out + rb + oc + 128) = *(const float4*)&ldsF[orow * LSO + oc + 128];
    __syncthreads();
  }
}

// ---------------- fused proj GEMM + residual + LayerNorm2 -> x2n ----------------
// 2-phase global_load_lds pipeline (5 loads/stage -> vmcnt(5)).
__global__ __launch_bounds__(256) void proj_ln(
    const u16* __restrict__ A, const u16* __restrict__ Bt, const float* __restrict__ bias,
    const u16* __restrict__ res, const float* __restrict__ gam, const float* __restrict__ bet,
    u16* __restrict__ x2n)
{
  __shared__ __align__(16) u16 lds[20480];
  int tid = threadIdx.x;
  int w = tid >> 6, lane = tid & 63;
  int quad = lane >> 4, c = lane & 15;
  int mt = blockIdx.x;
  int wn = w * 64;
  const u16* Abase = A + (size_t)mt * 64 * 256;
  int an = tid & 63, aj = tid >> 6;
  f32x4 zero = {0.f, 0.f, 0.f, 0.f};
  f32x4 acc[4][4];
  #pragma unroll
  for (int mi = 0; mi < 4; mi++)
    #pragma unroll
    for (int ni = 0; ni < 4; ni++) acc[mi][ni] = zero;

  auto stage = [&](int buf, int k0){
    u16* base = &lds[buf * 10240];
    GLL(Abase + (size_t)an * 256 + k0 + aj * 8, &base[tid * 8]);
    #pragma unroll
    for (int i = 0; i < 4; i++){
      int ci = tid + i * 256;
      int n = ci & 255, jjb = ci >> 8;
      GLL(Bt + (size_t)n * 256 + k0 + jjb * 8, &base[2048 + ci * 8]);
    }
  };
  auto compute = [&](int cb){
    const u16* base = &lds[cb * 10240];
    s16x8 af[4], bfr[4];
    #pragma unroll
    for (int mi = 0; mi < 4; mi++)
      af[mi] = *(const s16x8*)&base[(quad * 64 + mi * 16 + c) * 8];
    #pragma unroll
    for (int ni = 0; ni < 4; ni++)
      bfr[ni] = *(const s16x8*)&base[2048 + (quad * 256 + wn + ni * 16 + c) * 8];
    #pragma unroll
    for (int mi = 0; mi < 4; mi++)
      #pragma unroll
      for (int ni = 0; ni < 4; ni++)
        acc[mi][ni] = MFMA_BF16(af[mi], bfr[ni], acc[mi][ni]);
  };

  stage(0, 0);
  int cur = 0;
  for (int k0 = 32; k0 < 256; k0 += 32){
    stage(cur ^ 1, k0);
    PIPE_WAIT_BAR(5);
    compute(cur);
    PIPE_BAR();
    cur ^= 1;
  }
  PIPE_WAIT_BAR(0);
  compute(cur);
  __syncthreads();

  #pragma unroll
  for (int ni = 0; ni < 4; ni++){
    int col = wn + ni * 16 + c;
    float bv = bias[col];
    #pragma unroll
    for (int mi = 0; mi < 4; mi++){
      #pragma unroll
      for (int r = 0; r < 4; r++){
        int rowL = mi * 16 + quad * 4 + r;
        size_t gidx = ((size_t)mt * 64 + rowL) * 256 + col;
        lds[rowL * 264 + col] = f2b(acc[mi][ni][r] + bv + b2f(res[gidx]));
      }
    }
  }
  __syncthreads();

  int rowL = tid >> 2, part = (tid & 3) * 64;
  float s = 0.f, s2 = 0.f;
  #pragma unroll
  for (int i = 0; i < 16; i++){
    ushort4 u = *(const ushort4*)&lds[rowL * 264 + part + i * 4];
    float v0 = b2f(u.x), v1 = b2f(u.y), v2 = b2f(u.z), v3 = b2f(u.w);
    s  += v0 + v1 + v2 + v3;
    s2 += v0*v0 + v1*v1 + v2*v2 + v3*v3;
  }
  s  += __shfl_xor(s, 1);  s  += __shfl_xor(s, 2);
  s2 += __shfl_xor(s2, 1); s2 += __shfl_xor(s2, 2);
  float mean = s * (1.0f/256.0f);
  float var  = s2 * (1.0f/256.0f) - mean*mean;
  float rs   = rsqrtf(var + 1e-5f);
  size_t orow = ((size_t)mt * 64 + rowL) * 256;
  #pragma unroll
  for (int i = 0; i < 16; i++){
    int col = part + i * 4;
    ushort4 u = *(const ushort4*)&lds[rowL * 264 + col];
    float4 g4 = *(const float4*)(gam + col);
    float4 b4 = *(const float4*)(bet + col);
    ushort4 o;
    o.x = f2b((b2f(u.x) - mean)*rs*g4.x + b4.x);
    o.y = f2b((b2f(u.y) - mean)*rs*g4.y + b4.y);
    o.z = f2b((b2f(u.z) - mean)*rs*g4.z + b4.z);
    o.w = f2b((b2f(u.w) - mean)*rs*g4.w + b4.w);
    *(ushort4*)(x2n + orow + col) = o;
  }
}

// ---------------- flash attention, no-max softmax; XCD-swizzled 1D grid ----------------
__global__ __launch_bounds__(256) void attn_kernel(const u16* __restrict__ q,
    const u16* __restrict__ k, const u16* __restrict__ v, u16* __restrict__ y)
{
  __shared__ __align__(16) u16 ldsK[32 * 36];    // [s][d], row stride 36
  __shared__ __align__(16) u16 ldsV[32 * 36];    // [d][s], row stride 36
  __shared__ __align__(16) u16 ldsp[4][16 * 36]; // per-wave P [prow][s], stride 36
  int tid = threadIdx.x;
  int w = tid >> 6, lane = tid & 63;
  int quad = lane >> 4, c = lane & 15;
  int bid = blockIdx.x;
  int x = bid & 7, j = bid >> 3;
  int qt = j & 3, bah = (j >> 2) * 8 + x;
  int q0 = qt * 128 + w * 32;
  const u16* qb = q + (size_t)bah * 16384;
  const u16* kb = k + (size_t)bah * 16384;
  const u16* vb = v + (size_t)bah * 16384;
  int krow = tid >> 3, kcol = (tid & 7) * 4;     // K staging: uint2 per thread
  int vd = tid & 31,  vs = (tid >> 5) * 4;       // V staging: 4 strided u16 -> b64

  s16x8 qf0 = *(const s16x8*)(qb + (q0 + c) * 32 + quad * 8);
  s16x8 qf1 = *(const s16x8*)(qb + (q0 + 16 + c) * 32 + quad * 8);
  float l0[4] = {0.f,0.f,0.f,0.f}, l1[4] = {0.f,0.f,0.f,0.f};
  f32x4 o00 = {0,0,0,0}, o01 = {0,0,0,0}, o10 = {0,0,0,0}, o11 = {0,0,0,0};
  f32x4 zero = {0,0,0,0};

  for (int s0 = 0; s0 < 512; s0 += 32){
    uint2 kr = *(const uint2*)(kb + (s0 + krow) * 32 + kcol);
    short4 vr;
    vr.x = (short)vb[(s0 + vs)     * 32 + vd];
    vr.y = (short)vb[(s0 + vs + 1) * 32 + vd];
    vr.z = (short)vb[(s0 + vs + 2) * 32 + vd];
    vr.w = (short)vb[(s0 + vs + 3) * 32 + vd];
    __syncthreads();
    *(uint2*)&ldsK[krow * 36 + kcol] = kr;
    *(short4*)&ldsV[vd * 36 + vs]   = vr;
    __syncthreads();

    s16x8 kf0 = *(const s16x8*)&ldsK[c * 36 + quad * 8];
    s16x8 kf1 = *(const s16x8*)&ldsK[(16 + c) * 36 + quad * 8];
    s16x8 vf0 = *(const s16x8*)&ldsV[c * 36 + quad * 8];
    s16x8 vf1 = *(const s16x8*)&ldsV[(16 + c) * 36 + quad * 8];

    f32x4 S0 = MFMA_BF16(qf0, kf0, zero);
    f32x4 S1 = MFMA_BF16(qf0, kf1, zero);
    #pragma unroll
    for (int r = 0; r < 4; r++){
      float p0 = __expf(S0[r]), p1 = __expf(S1[r]);
      l0[r] += p0 + p1;
      int prow = quad * 4 + r;
      ldsp[w][prow * 36 + c]      = f2b_trunc(p0);
      ldsp[w][prow * 36 + 16 + c] = f2b_trunc(p1);
    }
    s16x8 pf = *(const s16x8*)&ldsp[w][c * 36 + quad * 8];
    o00 = MFMA_BF16(pf, vf0, o00);
    o01 = MFMA_BF16(pf, vf1, o01);

    S0 = MFMA_BF16(qf1, kf0, zero);
    S1 = MFMA_BF16(qf1, kf1, zero);
    #pragma unroll
    for (int r = 0; r < 4; r++){
      float p0 = __expf(S0[r]), p1 = __expf(S1[r]);
      l1[r] += p0 + p1;
      int prow = quad * 4 + r;
      ldsp[w][prow * 36 + c]      = f2b_trunc(p0);
      ldsp[w][prow * 36 + 16 + c] = f2b_trunc(p1);
    }
    pf = *(const s16x8*)&ldsp[w][c * 36 + quad * 8];
    o10 = MFMA_BF16(pf, vf0, o10);
    o11 = MFMA_BF16(pf, vf1, o11);
  }

  #pragma unroll
  for (int r = 0; r < 4; r++){
    #pragma unroll
    for (int off = 8; off; off >>= 1){
      l0[r] += __shfl_xor(l0[r], off);
      l1[r] += __shfl_xor(l1[r], off);
    }
  }

  int ba = bah >> 3, hh = bah & 7;
  #pragma unroll
  for (int r = 0; r < 4; r++){
    int t0 = q0 + quad * 4 + r;
    float inv0 = 1.0f / l0[r], inv1 = 1.0f / l1[r];
    size_t base0 = ((size_t)(ba * 512 + t0)) * 256 + hh * 32;
    size_t base1 = base0 + 16 * 256;
    y[base0 + c]      = f2b(o00[r] * inv0);
    y[base0 + 16 + c] = f2b(o01[r] * inv0);
    y[base1 + c]      = f2b(o10[r] * inv1);
    y[base1 + 16 + c] = f2b(o11[r] * inv1);
  }
}

// ---------------- launch ----------------
extern "C" void kernel_launch(void* const* d_in, const int* in_sizes, int n_in,
                              void* d_out, int out_size, void* d_ws, size_t ws_size,
                              hipStream_t stream)
{
  const float* x      = (const float*)d_in[0];
  const float* ln1_w  = (const float*)d_in[1];
  const float* ln1_b  = (const float*)d_in[2];
  const float* qkv_w  = (const float*)d_in[3];
  const float* qkv_b  = (const float*)d_in[4];
  const float* proj_w = (const float*)d_in[5];
  const float* proj_b = (const float*)d_in[6];
  const float* ln2_w  = (const float*)d_in[7];
  const float* ln2_b  = (const float*)d_in[8];
  const float* fc_w   = (const float*)d_in[9];
  const float* fc_b   = (const float*)d_in[10];
  const float* fc2_w  = (const float*)d_in[11];
  const float* fc2_b  = (const float*)d_in[12];
  float* out = (float*)d_out;
  char* ws = (char*)d_ws;

  // ws layout (bytes):
  // [0,32M) xn | [32M,166M) q|k|v|y | [166M,200M) x2n | [200M,~201M) weights
  u16* xn   = (u16*)ws;
  u16* qb   = (u16*)(ws + (size_t)33554432);
  u16* kb   = qb + 16777216;
  u16* vb   = kb + 16777216;
  u16* yb   = vb + 16777216;
  u16* x2n  = (u16*)(ws + (size_t)173015040);
  u16* wqkvT  = (u16*)(ws + (size_t)206569472);
  u16* wprojT = wqkvT + 196608;
  u16* wfcT   = wprojT + 65536;
  u16* wfc2T  = wfcT + 262144;

  wconv_all<<<3072, 256, 0, stream>>>(qkv_w, wqkvT, proj_w, wprojT, fc_w, wfcT, fc2_w, wfc2T);

  ln_f32<<<16384, 256, 0, stream>>>(x, ln1_w, ln1_b, xn);
  gemm128<0,6><<<3072, 256, 0, stream>>>(xn, wqkvT, qkv_b, nullptr, qb, kb, vb, 768, 256);
  attn_kernel<<<4096, 256, 0, stream>>>(qb, kb, vb, yb);
  proj_ln<<<1024, 256, 0, stream>>>(yb, wprojT, proj_b, xn, ln2_w, ln2_b, x2n);
  ffn_fused<<<1024, 512, 0, stream>>>(x2n, wfcT, fc_b, wfc2T, fc2_b, out);
}